// Round 8
// baseline (612.529 us; speedup 1.0000x reference)
//
#include <hip/hip_runtime.h>

#define B_SZ   4096
#define T_SZ   512
#define F_SZ   32
#define S_SZ   64
#define H_SZ   128
#define OUT_SZ 32
#define PH_SZ  6

#define ROWS    8     // batch rows per block (half MFMA width) -> 512 blocks, 2/CU
#define THREADS 256   // 4 waves; wave wv owns states [16wv, 16wv+16)

typedef __attribute__((ext_vector_type(8))) _Float16 f16x8;
typedef __attribute__((ext_vector_type(2))) __fp16 fp16v2;
typedef __attribute__((ext_vector_type(4))) float f32x4;

union F16Frag { _Float16 h[8]; f16x8 v; uint u[4]; };
union H2U { fp16v2 h; uint u; };

// one v_cvt_pkrtz_f16_f32: packs two f32 -> 2x f16 in a dword
__device__ __forceinline__ uint pk16(float a, float b) {
  H2U x; x.h = __builtin_amdgcn_cvt_pkrtz(a, b); return x.u;
}

#define MFMA(a, b, c) __builtin_amdgcn_mfma_f32_16x16x32_f16((a), (b), (c), 0, 0, 0)

// barrier WITHOUT vmcnt drain: LDS writes visible, global prefetch stays in flight
#define WAVE_BARRIER() do { \
    asm volatile("s_waitcnt lgkmcnt(0)" ::: "memory"); \
    __builtin_amdgcn_s_barrier(); \
    asm volatile("" ::: "memory"); \
  } while (0)

__global__ __launch_bounds__(THREADS, 2) void ssm_f16_kernel(
    const float* __restrict__ x, const float* __restrict__ pl,
    const float* __restrict__ W_A, const float* __restrict__ W_B,
    const float* __restrict__ W_C, const float* __restrict__ b_C,
    const float* __restrict__ W_ctrl, const float* __restrict__ b_ctrl,
    const float* __restrict__ W1, const float* __restrict__ b1,
    const float* __restrict__ W2, const float* __restrict__ b2,
    float* __restrict__ out) {
  // state exchange: [buf][col*128 + swizzled(k*2)]; 64 states fp16 per col
  __shared__ __align__(16) char  s_state[2][2048];   // 4 KB
  __shared__ __align__(16) float s_final[16][68];
  __shared__ __align__(16) float s_obs[ROWS][132];
  __shared__ __align__(16) float s_h1[ROWS][132];

  const int tid  = threadIdx.x;
  const int lane = tid & 63;
  const int wv   = tid >> 6;     // state tile: rows 16wv..16wv+15
  const int l15  = lane & 15;    // batch col (only 0..7 valid)
  const int g    = lane >> 4;    // k-group / D row group
  const int rb   = blockIdx.x * ROWS;
  const int rg   = min(rb + l15, B_SZ - 1);   // clamp for lanes 8..15 of last block
  const float SC = 2.8853900817779268f;       // 2*log2(e): folds tanh exp arg

  // ---- weight frags: A = fp16(hi) + fp16(residual); W_B fp16 single ----
  F16Frag Ah0, Ah1, Al0, Al1, Wbf;
  {
#pragma unroll
    for (int kh = 0; kh < 2; ++kh) {
      const float* ap = W_A + (size_t)(16 * wv + l15) * S_SZ + 32 * kh + 8 * g;
      F16Frag hi, lo;
#pragma unroll
      for (int j = 0; j < 8; ++j) {
        float f = ap[j] * SC;
        _Float16 h = (_Float16)f;       // RNE
        hi.h[j] = h;
        lo.h[j] = (_Float16)(f - (float)h);
      }
      if (kh == 0) { Ah0 = hi; Al0 = lo; } else { Ah1 = hi; Al1 = lo; }
    }
    const float* wp = W_B + (size_t)(16 * wv + l15) * F_SZ + 8 * g;
#pragma unroll
    for (int j = 0; j < 8; ++j) Wbf.h[j] = (_Float16)(wp[j] * SC);
  }

  // ---- control (SC-scaled), C/D layout: lane holds states 16wv+4g+q, col rg ----
  f32x4 ctrl;
#pragma unroll
  for (int q = 0; q < 4; ++q) {
    const int i = 16 * wv + 4 * g + q;
    float c = b_ctrl[i];
#pragma unroll
    for (int p = 0; p < PH_SZ; ++p)
      c = fmaf(W_ctrl[i * PH_SZ + p], pl[(size_t)rg * PH_SZ + p], c);
    ctrl[q] = c * SC;
  }

  // x: lane reads x[rg][t][8g .. 8g+7]
  const float* xg = x + (size_t)rg * T_SZ * F_SZ + 8 * g;

  // LDS offsets, XOR-swizzled (<=2-way conflicts on both sides)
  const int swz    = (l15 & 7) << 4;
  const int wr_off = l15 * 128 + ((wv * 32 + g * 8) ^ swz);       // 8B write
  const int rd0    = l15 * 128 + ((g * 16) ^ swz);                // k=8g..8g+7
  const int rd1    = l15 * 128 + ((64 + g * 16) ^ swz);           // k=32+8g..

  const f32x4 zero4 = {0.f, 0.f, 0.f, 0.f};
  f16x8 sh0, sh1;
#pragma unroll
  for (int j = 0; j < 8; ++j) { sh0[j] = (_Float16)0.f; sh1[j] = (_Float16)0.f; }

  // ---- prologue: base for t=0; prefetch x[1] (xB), x[2] (xA) ----
  f32x4 base;
  {
    float4 f0 = *(const float4*)(xg);
    float4 f1 = *(const float4*)(xg + 4);
    F16Frag xf;
    xf.u[0] = pk16(f0.x, f0.y); xf.u[1] = pk16(f0.z, f0.w);
    xf.u[2] = pk16(f1.x, f1.y); xf.u[3] = pk16(f1.z, f1.w);
    base = MFMA(Wbf.v, xf.v, ctrl);
  }
  float4 xB0 = *(const float4*)(xg + F_SZ);
  float4 xB1 = *(const float4*)(xg + F_SZ + 4);
  float4 xA0 = *(const float4*)(xg + 2 * F_SZ);
  float4 xA1 = *(const float4*)(xg + 2 * F_SZ + 4);

  // STEP(T_): state T_ -> T_+1. X regs hold x[T_+1] (for next base); reload x[T_+3].
#define STEP(T_, X0_, X1_, NB_, LAST_)                                          \
  {                                                                             \
    f32x4 P = MFMA(Ah0.v, sh0, base);                                           \
    f32x4 Q = MFMA(Al0.v, sh0, zero4);                                          \
    P = MFMA(Ah1.v, sh1, P);                                                    \
    Q = MFMA(Al1.v, sh1, Q);                                                    \
    float v0, v1, v2, v3;                                                       \
    {                                                                           \
      float z0 = P[0] + Q[0], z1 = P[1] + Q[1];                                 \
      float z2 = P[2] + Q[2], z3 = P[3] + Q[3];                                 \
      v0 = fmaf(-2.0f, __builtin_amdgcn_rcpf(__builtin_amdgcn_exp2f(z0) + 1.0f), 1.0f); \
      v1 = fmaf(-2.0f, __builtin_amdgcn_rcpf(__builtin_amdgcn_exp2f(z1) + 1.0f), 1.0f); \
      v2 = fmaf(-2.0f, __builtin_amdgcn_rcpf(__builtin_amdgcn_exp2f(z2) + 1.0f), 1.0f); \
      v3 = fmaf(-2.0f, __builtin_amdgcn_rcpf(__builtin_amdgcn_exp2f(z3) + 1.0f), 1.0f); \
    }                                                                           \
    *(uint2*)(&s_state[NB_][wr_off]) = make_uint2(pk16(v0, v1), pk16(v2, v3));  \
    if (LAST_)                                                                  \
      *(float4*)(&s_final[l15][16 * wv + 4 * g]) = make_float4(v0, v1, v2, v3); \
    WAVE_BARRIER();                                                             \
    sh0 = *(const f16x8*)(&s_state[NB_][rd0]);                                  \
    sh1 = *(const f16x8*)(&s_state[NB_][rd1]);                                  \
    /* next base in the ds_read shadow */                                       \
    F16Frag xf;                                                                 \
    xf.u[0] = pk16(X0_.x, X0_.y); xf.u[1] = pk16(X0_.z, X0_.w);                 \
    xf.u[2] = pk16(X1_.x, X1_.y); xf.u[3] = pk16(X1_.z, X1_.w);                 \
    {                                                                           \
      const int tn_ = ((T_) + 3) & (T_SZ - 1);                                  \
      X0_ = *(const float4*)(xg + (size_t)tn_ * F_SZ);                          \
      X1_ = *(const float4*)(xg + (size_t)tn_ * F_SZ + 4);                      \
    }                                                                           \
    base = MFMA(Wbf.v, xf.v, ctrl);                                             \
  }

  for (int t = 0; t < T_SZ; t += 2) {
    STEP(t,     xB0, xB1, 1, false)
    STEP(t + 1, xA0, xA1, 0, (t == T_SZ - 2))
  }
#undef STEP

  // ---- tail projections (8 rows) ----
  __syncthreads();
  const int rt = tid >> 5;   // 0..7
  const int ct = tid & 31;   // 0..31

#pragma unroll
  for (int k = 0; k < 4; ++k) {
    const int h = ct + 32 * k;
    float acc = b_C[h];
    const float4* wc = (const float4*)(W_C + (size_t)h * S_SZ);
    const float4* sv = (const float4*)(&s_final[rt][0]);
#pragma unroll
    for (int j = 0; j < S_SZ / 4; ++j) {
      float4 w = wc[j]; float4 s = sv[j];
      acc = fmaf(w.x, s.x, acc); acc = fmaf(w.y, s.y, acc);
      acc = fmaf(w.z, s.z, acc); acc = fmaf(w.w, s.w, acc);
    }
    s_obs[rt][h] = acc;
  }
  __syncthreads();

#pragma unroll
  for (int k = 0; k < 4; ++k) {
    const int h = ct + 32 * k;
    float acc = b1[h];
    const float4* w1p = (const float4*)(W1 + (size_t)h * H_SZ);
    const float4* ov  = (const float4*)(&s_obs[rt][0]);
#pragma unroll
    for (int j = 0; j < H_SZ / 4; ++j) {
      float4 w = w1p[j]; float4 o = ov[j];
      acc = fmaf(w.x, o.x, acc); acc = fmaf(w.y, o.y, acc);
      acc = fmaf(w.z, o.z, acc); acc = fmaf(w.w, o.w, acc);
    }
    s_h1[rt][h] = fmaxf(acc, 0.0f);
  }
  __syncthreads();

  {
    float acc = b2[ct];
    const float4* w2p = (const float4*)(W2 + (size_t)ct * H_SZ);
    const float4* hv  = (const float4*)(&s_h1[rt][0]);
#pragma unroll
    for (int j = 0; j < H_SZ / 4; ++j) {
      float4 w = w2p[j]; float4 h = hv[j];
      acc = fmaf(w.x, h.x, acc); acc = fmaf(w.y, h.y, acc);
      acc = fmaf(w.z, h.z, acc); acc = fmaf(w.w, h.w, acc);
    }
    out[(size_t)(rb + rt) * OUT_SZ + ct] = acc;
  }
}

extern "C" void kernel_launch(void* const* d_in, const int* in_sizes, int n_in,
                              void* d_out, int out_size, void* d_ws, size_t ws_size,
                              hipStream_t stream) {
  (void)in_sizes; (void)n_in; (void)out_size; (void)d_ws; (void)ws_size;
  const float* x      = (const float*)d_in[0];
  const float* pl     = (const float*)d_in[1];
  const float* W_A    = (const float*)d_in[2];
  const float* W_B    = (const float*)d_in[3];
  const float* W_C    = (const float*)d_in[4];
  const float* b_C    = (const float*)d_in[5];
  const float* W_ctrl = (const float*)d_in[6];
  const float* b_ctrl = (const float*)d_in[7];
  const float* W1     = (const float*)d_in[8];
  const float* b1     = (const float*)d_in[9];
  const float* W2     = (const float*)d_in[10];
  const float* b2     = (const float*)d_in[11];
  float* out = (float*)d_out;

  dim3 grid(B_SZ / ROWS);   // 512 blocks -> 2 blocks/CU -> 2 indep waves/SIMD
  dim3 block(THREADS);
  hipLaunchKernelGGL(ssm_f16_kernel, grid, block, 0, stream,
                     x, pl, W_A, W_B, W_C, b_C, W_ctrl, b_ctrl,
                     W1, b1, W2, b2, out);
}

// Round 9
// 368.884 us; speedup vs baseline: 1.6605x; 1.6605x over previous
//
#include <hip/hip_runtime.h>

#define B_SZ   4096
#define T_SZ   512
#define F_SZ   32
#define S_SZ   64
#define H_SZ   128
#define OUT_SZ 32
#define PH_SZ  6

#define ROWS    16    // batch rows per block -> 256 blocks (1/CU), no duplication
#define THREADS 256   // 4 waves; wave wv owns states [16wv, 16wv+16)

typedef __attribute__((ext_vector_type(8))) _Float16 f16x8;
typedef __attribute__((ext_vector_type(2))) __fp16 fp16v2;
typedef __attribute__((ext_vector_type(4))) float f32x4;

union F16Frag { _Float16 h[8]; f16x8 v; uint u[4]; };
union H2U { fp16v2 h; uint u; };

// one v_cvt_pkrtz_f16_f32: packs two f32 -> 2x f16 in a dword
__device__ __forceinline__ uint pk16(float a, float b) {
  H2U x; x.h = __builtin_amdgcn_cvt_pkrtz(a, b); return x.u;
}

#define MFMA(a, b, c) __builtin_amdgcn_mfma_f32_16x16x32_f16((a), (b), (c), 0, 0, 0)

// barrier WITHOUT vmcnt drain: LDS writes visible, global prefetch stays in flight
#define WAVE_BARRIER() do { \
    asm volatile("s_waitcnt lgkmcnt(0)" ::: "memory"); \
    __builtin_amdgcn_s_barrier(); \
    asm volatile("" ::: "memory"); \
  } while (0)

__global__ __launch_bounds__(THREADS, 2) void ssm_f16b_kernel(
    const float* __restrict__ x, const float* __restrict__ pl,
    const float* __restrict__ W_A, const float* __restrict__ W_B,
    const float* __restrict__ W_C, const float* __restrict__ b_C,
    const float* __restrict__ W_ctrl, const float* __restrict__ b_ctrl,
    const float* __restrict__ W1, const float* __restrict__ b1,
    const float* __restrict__ W2, const float* __restrict__ b2,
    float* __restrict__ out) {
  // state exchange: [buf][col*128 + swizzled(k*2)]; 64 fp16 states per col
  __shared__ __align__(16) char  s_state[2][2048];   // 4 KB
  __shared__ __align__(16) float s_final[ROWS][68];
  __shared__ __align__(16) float s_obs[ROWS][132];
  __shared__ __align__(16) float s_h1[ROWS][132];

  const int tid  = threadIdx.x;
  const int lane = tid & 63;
  const int wv   = tid >> 6;     // state tile: rows 16wv..16wv+15
  const int l15  = lane & 15;    // batch col
  const int g    = lane >> 4;    // k-group / D row group
  const int rb   = blockIdx.x * ROWS;
  const int rg   = rb + l15;
  const float SC = 2.8853900817779268f;   // 2*log2(e): folds tanh exp arg

  // ---- weight frags: A = fp16(hi) + fp16(residual); W_B fp16 single ----
  F16Frag Ah0, Ah1, Al0, Al1, Wbf;
  {
#pragma unroll
    for (int kh = 0; kh < 2; ++kh) {
      const float* ap = W_A + (size_t)(16 * wv + l15) * S_SZ + 32 * kh + 8 * g;
      F16Frag hi, lo;
#pragma unroll
      for (int j = 0; j < 8; ++j) {
        float f = ap[j] * SC;
        _Float16 h = (_Float16)f;     // RNE
        hi.h[j] = h;
        lo.h[j] = (_Float16)(f - (float)h);
      }
      if (kh == 0) { Ah0 = hi; Al0 = lo; } else { Ah1 = hi; Al1 = lo; }
    }
    const float* wp = W_B + (size_t)(16 * wv + l15) * F_SZ + 8 * g;
#pragma unroll
    for (int j = 0; j < 8; ++j) Wbf.h[j] = (_Float16)(wp[j] * SC);
  }

  // ---- control (SC-scaled), C/D layout: lane holds states 16wv+4g+q, col rg ----
  f32x4 ctrl;
#pragma unroll
  for (int q = 0; q < 4; ++q) {
    const int i = 16 * wv + 4 * g + q;
    float c = b_ctrl[i];
#pragma unroll
    for (int p = 0; p < PH_SZ; ++p)
      c = fmaf(W_ctrl[i * PH_SZ + p], pl[(size_t)rg * PH_SZ + p], c);
    ctrl[q] = c * SC;
  }

  // x: lane reads x[rg][t][8g .. 8g+7]
  const float* xg = x + (size_t)rg * T_SZ * F_SZ + 8 * g;

  // LDS offsets, XOR-swizzled
  const int swz    = (l15 & 7) << 4;
  const int wr_off = l15 * 128 + ((wv * 32 + g * 8) ^ swz);   // 8B write
  const int rd0    = l15 * 128 + ((g * 16) ^ swz);            // k=8g..8g+7
  const int rd1    = l15 * 128 + ((64 + g * 16) ^ swz);       // k=32+8g..

  const f32x4 zero4 = {0.f, 0.f, 0.f, 0.f};
  f16x8 sh0, sh1;
#pragma unroll
  for (int j = 0; j < 8; ++j) { sh0[j] = (_Float16)0.f; sh1[j] = (_Float16)0.f; }

  // ---- prologue: base for t=0; prefetch x[1] (xB), x[2] (xA) ----
  f32x4 base;
  {
    float4 f0 = *(const float4*)(xg);
    float4 f1 = *(const float4*)(xg + 4);
    F16Frag xf;
    xf.u[0] = pk16(f0.x, f0.y); xf.u[1] = pk16(f0.z, f0.w);
    xf.u[2] = pk16(f1.x, f1.y); xf.u[3] = pk16(f1.z, f1.w);
    base = MFMA(Wbf.v, xf.v, ctrl);
  }
  float4 xB0 = *(const float4*)(xg + F_SZ);
  float4 xB1 = *(const float4*)(xg + F_SZ + 4);
  float4 xA0 = *(const float4*)(xg + 2 * F_SZ);
  float4 xA1 = *(const float4*)(xg + 2 * F_SZ + 4);

  // STEP(T_): state T_ -> T_+1. Four INDEPENDENT MFMAs; base joins via VALU.
  // X regs hold x[T_+1] (consumed for next base); reloaded with x[T_+3].
#define STEP(T_, X0_, X1_, NB_, LAST_)                                          \
  {                                                                             \
    f32x4 P0 = MFMA(Ah0.v, sh0, zero4);                                         \
    f32x4 Q0 = MFMA(Al0.v, sh0, zero4);                                         \
    f32x4 P1 = MFMA(Ah1.v, sh1, zero4);                                         \
    f32x4 Q1 = MFMA(Al1.v, sh1, zero4);                                         \
    float v0, v1, v2, v3;                                                       \
    {                                                                           \
      f32x4 S = (P0 + P1) + ((Q0 + Q1) + base);                                 \
      v0 = fmaf(-2.0f, __builtin_amdgcn_rcpf(__builtin_amdgcn_exp2f(S[0]) + 1.0f), 1.0f); \
      v1 = fmaf(-2.0f, __builtin_amdgcn_rcpf(__builtin_amdgcn_exp2f(S[1]) + 1.0f), 1.0f); \
      v2 = fmaf(-2.0f, __builtin_amdgcn_rcpf(__builtin_amdgcn_exp2f(S[2]) + 1.0f), 1.0f); \
      v3 = fmaf(-2.0f, __builtin_amdgcn_rcpf(__builtin_amdgcn_exp2f(S[3]) + 1.0f), 1.0f); \
    }                                                                           \
    *(uint2*)(&s_state[NB_][wr_off]) = make_uint2(pk16(v0, v1), pk16(v2, v3));  \
    if (LAST_)                                                                  \
      *(float4*)(&s_final[l15][16 * wv + 4 * g]) = make_float4(v0, v1, v2, v3); \
    WAVE_BARRIER();                                                             \
    sh0 = *(const f16x8*)(&s_state[NB_][rd0]);                                  \
    sh1 = *(const f16x8*)(&s_state[NB_][rd1]);                                  \
    /* next base in the ds_read shadow (latency hidden under next P/Q+barrier) */\
    F16Frag xf;                                                                 \
    xf.u[0] = pk16(X0_.x, X0_.y); xf.u[1] = pk16(X0_.z, X0_.w);                 \
    xf.u[2] = pk16(X1_.x, X1_.y); xf.u[3] = pk16(X1_.z, X1_.w);                 \
    {                                                                           \
      const int tn_ = ((T_) + 3) & (T_SZ - 1);                                  \
      X0_ = *(const float4*)(xg + (size_t)tn_ * F_SZ);                          \
      X1_ = *(const float4*)(xg + (size_t)tn_ * F_SZ + 4);                      \
    }                                                                           \
    base = MFMA(Wbf.v, xf.v, ctrl);                                             \
  }

  for (int t = 0; t < T_SZ; t += 2) {
    STEP(t,     xB0, xB1, 1, false)
    STEP(t + 1, xA0, xA1, 0, (t == T_SZ - 2))
  }
#undef STEP

  // ---- tail projections ----
  __syncthreads();
  const int rt = tid >> 4;
  const int ct = tid & 15;

#pragma unroll
  for (int k = 0; k < 8; ++k) {
    const int h = ct + 16 * k;
    float acc = b_C[h];
    const float4* wc = (const float4*)(W_C + (size_t)h * S_SZ);
    const float4* sv = (const float4*)(&s_final[rt][0]);
#pragma unroll
    for (int j = 0; j < S_SZ / 4; ++j) {
      float4 w = wc[j]; float4 s = sv[j];
      acc = fmaf(w.x, s.x, acc); acc = fmaf(w.y, s.y, acc);
      acc = fmaf(w.z, s.z, acc); acc = fmaf(w.w, s.w, acc);
    }
    s_obs[rt][h] = acc;
  }
  __syncthreads();

#pragma unroll
  for (int k = 0; k < 8; ++k) {
    const int h = ct + 16 * k;
    float acc = b1[h];
    const float4* w1p = (const float4*)(W1 + (size_t)h * H_SZ);
    const float4* ov  = (const float4*)(&s_obs[rt][0]);
#pragma unroll
    for (int j = 0; j < H_SZ / 4; ++j) {
      float4 w = w1p[j]; float4 o = ov[j];
      acc = fmaf(w.x, o.x, acc); acc = fmaf(w.y, o.y, acc);
      acc = fmaf(w.z, o.z, acc); acc = fmaf(w.w, o.w, acc);
    }
    s_h1[rt][h] = fmaxf(acc, 0.0f);
  }
  __syncthreads();

#pragma unroll
  for (int it = 0; it < 2; ++it) {
    const int idx = tid + 256 * it;
    const int r = idx >> 5;
    const int c = idx & 31;
    float acc = b2[c];
    const float4* w2p = (const float4*)(W2 + (size_t)c * H_SZ);
    const float4* hv  = (const float4*)(&s_h1[r][0]);
#pragma unroll
    for (int j = 0; j < H_SZ / 4; ++j) {
      float4 w = w2p[j]; float4 h = hv[j];
      acc = fmaf(w.x, h.x, acc); acc = fmaf(w.y, h.y, acc);
      acc = fmaf(w.z, h.z, acc); acc = fmaf(w.w, h.w, acc);
    }
    out[(size_t)(rb + r) * OUT_SZ + c] = acc;
  }
}

extern "C" void kernel_launch(void* const* d_in, const int* in_sizes, int n_in,
                              void* d_out, int out_size, void* d_ws, size_t ws_size,
                              hipStream_t stream) {
  (void)in_sizes; (void)n_in; (void)out_size; (void)d_ws; (void)ws_size;
  const float* x      = (const float*)d_in[0];
  const float* pl     = (const float*)d_in[1];
  const float* W_A    = (const float*)d_in[2];
  const float* W_B    = (const float*)d_in[3];
  const float* W_C    = (const float*)d_in[4];
  const float* b_C    = (const float*)d_in[5];
  const float* W_ctrl = (const float*)d_in[6];
  const float* b_ctrl = (const float*)d_in[7];
  const float* W1     = (const float*)d_in[8];
  const float* b1     = (const float*)d_in[9];
  const float* W2     = (const float*)d_in[10];
  const float* b2     = (const float*)d_in[11];
  float* out = (float*)d_out;

  dim3 grid(B_SZ / ROWS);   // 256 blocks, 1/CU
  dim3 block(THREADS);
  hipLaunchKernelGGL(ssm_f16b_kernel, grid, block, 0, stream,
                     x, pl, W_A, W_B, W_C, b_C, W_ctrl, b_ctrl,
                     W1, b1, W2, b2, out);
}

// Round 10
// 285.684 us; speedup vs baseline: 2.1441x; 1.2912x over previous
//
#include <hip/hip_runtime.h>

#define B_SZ   4096
#define T_SZ   512
#define F_SZ   32
#define S_SZ   64
#define H_SZ   128
#define OUT_SZ 32
#define PH_SZ  6

#define ROWS    16    // batch rows per block -> 256 blocks
#define THREADS 128   // 2 waves; wave w owns states [32w, 32w+32) (2 MFMA tiles)

typedef __attribute__((ext_vector_type(8))) _Float16 f16x8;
typedef __attribute__((ext_vector_type(2))) __fp16 fp16v2;
typedef __attribute__((ext_vector_type(4))) float f32x4;

union F16Frag { _Float16 h[8]; f16x8 v; uint u[4]; };
union H2U { fp16v2 h; uint u; };

// one v_cvt_pkrtz_f16_f32: packs two f32 -> 2x f16 in a dword
__device__ __forceinline__ uint pk16(float a, float b) {
  H2U x; x.h = __builtin_amdgcn_cvt_pkrtz(a, b); return x.u;
}

#define MFMA(a, b, c) __builtin_amdgcn_mfma_f32_16x16x32_f16((a), (b), (c), 0, 0, 0)

// barrier WITHOUT vmcnt drain: LDS writes visible, global prefetch stays in flight
#define WAVE_BARRIER() do { \
    asm volatile("s_waitcnt lgkmcnt(0)" ::: "memory"); \
    __builtin_amdgcn_s_barrier(); \
    asm volatile("" ::: "memory"); \
  } while (0)

__global__ __launch_bounds__(THREADS, 2) void ssm_2w_kernel(
    const float* __restrict__ x, const float* __restrict__ pl,
    const float* __restrict__ W_A, const float* __restrict__ W_B,
    const float* __restrict__ W_C, const float* __restrict__ b_C,
    const float* __restrict__ W_ctrl, const float* __restrict__ b_ctrl,
    const float* __restrict__ W1, const float* __restrict__ b1,
    const float* __restrict__ W2, const float* __restrict__ b2,
    float* __restrict__ out) {
  // state exchange: [buf][col*128 + swizzled(k*2)]; 64 fp16 states per col
  __shared__ __align__(16) char  s_state[2][2048];   // 4 KB
  __shared__ __align__(16) float s_final[ROWS][68];
  __shared__ __align__(16) float s_obs[ROWS][132];
  __shared__ __align__(16) float s_h1[ROWS][132];

  const int tid  = threadIdx.x;
  const int lane = tid & 63;
  const int wv2  = tid >> 6;     // 0..1: owns tiles {2wv2, 2wv2+1}
  const int l15  = lane & 15;    // batch col
  const int g    = lane >> 4;    // k-group / D row group
  const int rb   = blockIdx.x * ROWS;
  const int rg   = rb + l15;
  const float SC = 2.8853900817779268f;   // 2*log2(e): folds tanh exp arg

  // ---- weight frags: A single fp16 plane (no residual); W_B fp16 ----
  F16Frag Ah[2][2], Wb[2];
  f32x4 ctrl[2];
#pragma unroll
  for (int tt = 0; tt < 2; ++tt) {
    const int t = 2 * wv2 + tt;
#pragma unroll
    for (int kh = 0; kh < 2; ++kh) {
      const float* ap = W_A + (size_t)(16 * t + l15) * S_SZ + 32 * kh + 8 * g;
#pragma unroll
      for (int j = 0; j < 8; ++j) Ah[tt][kh].h[j] = (_Float16)(ap[j] * SC);
    }
    const float* wp = W_B + (size_t)(16 * t + l15) * F_SZ + 8 * g;
#pragma unroll
    for (int j = 0; j < 8; ++j) Wb[tt].h[j] = (_Float16)(wp[j] * SC);
    // control (SC-scaled), C/D layout: lane holds states 16t+4g+q, col rg
#pragma unroll
    for (int q = 0; q < 4; ++q) {
      const int i = 16 * t + 4 * g + q;
      float c = b_ctrl[i];
#pragma unroll
      for (int p = 0; p < PH_SZ; ++p)
        c = fmaf(W_ctrl[i * PH_SZ + p], pl[(size_t)rg * PH_SZ + p], c);
      ctrl[tt][q] = c * SC;
    }
  }

  // x: lane reads x[rg][t][8g .. 8g+7]
  const float* xg = x + (size_t)rg * T_SZ * F_SZ + 8 * g;

  // LDS offsets, XOR-swizzled. Write: 2x ds_write_b64 (one per tile).
  const int swz = (l15 & 7) << 4;
  const int wr0 = l15 * 128 + (((32 * wv2 + 4 * g) * 2) ^ swz);
  const int wr1 = l15 * 128 + (((32 * wv2 + 16 + 4 * g) * 2) ^ swz);
  const int rd0 = l15 * 128 + ((16 * g) ^ swz);          // k = 8g..8g+7
  const int rd1 = l15 * 128 + ((64 + 16 * g) ^ swz);     // k = 32+8g..

  f16x8 sh0, sh1;
#pragma unroll
  for (int j = 0; j < 8; ++j) { sh0[j] = (_Float16)0.f; sh1[j] = (_Float16)0.f; }

  // ---- prologue: base for t=0; prefetch x[1] (xB), x[2] (xA) ----
  f32x4 base0, base1;
  {
    float4 f0 = *(const float4*)(xg);
    float4 f1 = *(const float4*)(xg + 4);
    F16Frag xf;
    xf.u[0] = pk16(f0.x, f0.y); xf.u[1] = pk16(f0.z, f0.w);
    xf.u[2] = pk16(f1.x, f1.y); xf.u[3] = pk16(f1.z, f1.w);
    base0 = MFMA(Wb[0].v, xf.v, ctrl[0]);
    base1 = MFMA(Wb[1].v, xf.v, ctrl[1]);
  }
  float4 xB0 = *(const float4*)(xg + F_SZ);
  float4 xB1 = *(const float4*)(xg + F_SZ + 4);
  float4 xA0 = *(const float4*)(xg + 2 * F_SZ);
  float4 xA1 = *(const float4*)(xg + 2 * F_SZ + 4);

  // STEP(T_): state T_ -> T_+1. Two 2-deep MFMA chains (one per tile).
  // X regs hold x[T_+1] (consumed for next base); reloaded with x[T_+3].
#define STEP(T_, X0_, X1_, NB_, LAST_)                                          \
  {                                                                             \
    f32x4 P0 = MFMA(Ah[0][0].v, sh0, base0);                                    \
    f32x4 P1 = MFMA(Ah[1][0].v, sh0, base1);                                    \
    P0 = MFMA(Ah[0][1].v, sh1, P0);                                             \
    P1 = MFMA(Ah[1][1].v, sh1, P1);                                             \
    float v00, v01, v02, v03, v10, v11, v12, v13;                               \
    v00 = fmaf(-2.0f, __builtin_amdgcn_rcpf(__builtin_amdgcn_exp2f(P0[0]) + 1.0f), 1.0f); \
    v01 = fmaf(-2.0f, __builtin_amdgcn_rcpf(__builtin_amdgcn_exp2f(P0[1]) + 1.0f), 1.0f); \
    v02 = fmaf(-2.0f, __builtin_amdgcn_rcpf(__builtin_amdgcn_exp2f(P0[2]) + 1.0f), 1.0f); \
    v03 = fmaf(-2.0f, __builtin_amdgcn_rcpf(__builtin_amdgcn_exp2f(P0[3]) + 1.0f), 1.0f); \
    v10 = fmaf(-2.0f, __builtin_amdgcn_rcpf(__builtin_amdgcn_exp2f(P1[0]) + 1.0f), 1.0f); \
    v11 = fmaf(-2.0f, __builtin_amdgcn_rcpf(__builtin_amdgcn_exp2f(P1[1]) + 1.0f), 1.0f); \
    v12 = fmaf(-2.0f, __builtin_amdgcn_rcpf(__builtin_amdgcn_exp2f(P1[2]) + 1.0f), 1.0f); \
    v13 = fmaf(-2.0f, __builtin_amdgcn_rcpf(__builtin_amdgcn_exp2f(P1[3]) + 1.0f), 1.0f); \
    *(uint2*)(&s_state[NB_][wr0]) = make_uint2(pk16(v00, v01), pk16(v02, v03)); \
    *(uint2*)(&s_state[NB_][wr1]) = make_uint2(pk16(v10, v11), pk16(v12, v13)); \
    if (LAST_) {                                                                \
      *(float4*)(&s_final[l15][16 * (2 * wv2) + 4 * g]) =                       \
          make_float4(v00, v01, v02, v03);                                      \
      *(float4*)(&s_final[l15][16 * (2 * wv2 + 1) + 4 * g]) =                   \
          make_float4(v10, v11, v12, v13);                                      \
    }                                                                           \
    WAVE_BARRIER();                                                             \
    sh0 = *(const f16x8*)(&s_state[NB_][rd0]);                                  \
    sh1 = *(const f16x8*)(&s_state[NB_][rd1]);                                  \
    /* next base in the ds_read shadow */                                       \
    F16Frag xf;                                                                 \
    xf.u[0] = pk16(X0_.x, X0_.y); xf.u[1] = pk16(X0_.z, X0_.w);                 \
    xf.u[2] = pk16(X1_.x, X1_.y); xf.u[3] = pk16(X1_.z, X1_.w);                 \
    {                                                                           \
      const int tn_ = ((T_) + 3) & (T_SZ - 1);                                  \
      X0_ = *(const float4*)(xg + (size_t)tn_ * F_SZ);                          \
      X1_ = *(const float4*)(xg + (size_t)tn_ * F_SZ + 4);                      \
    }                                                                           \
    base0 = MFMA(Wb[0].v, xf.v, ctrl[0]);                                       \
    base1 = MFMA(Wb[1].v, xf.v, ctrl[1]);                                       \
  }

  for (int t = 0; t < T_SZ; t += 2) {
    STEP(t,     xB0, xB1, 1, false)
    STEP(t + 1, xA0, xA1, 0, (t == T_SZ - 2))
  }
#undef STEP

  // ---- tail projections (128 threads: 16 rows x 8 col-threads) ----
  __syncthreads();
  const int rt = tid >> 3;   // 0..15
  const int ct = tid & 7;    // 0..7

#pragma unroll
  for (int k = 0; k < 16; ++k) {
    const int h = ct + 8 * k;
    float acc = b_C[h];
    const float4* wc = (const float4*)(W_C + (size_t)h * S_SZ);
    const float4* sv = (const float4*)(&s_final[rt][0]);
#pragma unroll
    for (int j = 0; j < S_SZ / 4; ++j) {
      float4 w = wc[j]; float4 s = sv[j];
      acc = fmaf(w.x, s.x, acc); acc = fmaf(w.y, s.y, acc);
      acc = fmaf(w.z, s.z, acc); acc = fmaf(w.w, s.w, acc);
    }
    s_obs[rt][h] = acc;
  }
  __syncthreads();

#pragma unroll
  for (int k = 0; k < 16; ++k) {
    const int h = ct + 8 * k;
    float acc = b1[h];
    const float4* w1p = (const float4*)(W1 + (size_t)h * H_SZ);
    const float4* ov  = (const float4*)(&s_obs[rt][0]);
#pragma unroll
    for (int j = 0; j < H_SZ / 4; ++j) {
      float4 w = w1p[j]; float4 o = ov[j];
      acc = fmaf(w.x, o.x, acc); acc = fmaf(w.y, o.y, acc);
      acc = fmaf(w.z, o.z, acc); acc = fmaf(w.w, o.w, acc);
    }
    s_h1[rt][h] = fmaxf(acc, 0.0f);
  }
  __syncthreads();

#pragma unroll
  for (int it = 0; it < 4; ++it) {
    const int c = ct + 8 * it;
    float acc = b2[c];
    const float4* w2p = (const float4*)(W2 + (size_t)c * H_SZ);
    const float4* hv  = (const float4*)(&s_h1[rt][0]);
#pragma unroll
    for (int j = 0; j < H_SZ / 4; ++j) {
      float4 w = w2p[j]; float4 h = hv[j];
      acc = fmaf(w.x, h.x, acc); acc = fmaf(w.y, h.y, acc);
      acc = fmaf(w.z, h.z, acc); acc = fmaf(w.w, h.w, acc);
    }
    out[(size_t)(rb + rt) * OUT_SZ + c] = acc;
  }
}

extern "C" void kernel_launch(void* const* d_in, const int* in_sizes, int n_in,
                              void* d_out, int out_size, void* d_ws, size_t ws_size,
                              hipStream_t stream) {
  (void)in_sizes; (void)n_in; (void)out_size; (void)d_ws; (void)ws_size;
  const float* x      = (const float*)d_in[0];
  const float* pl     = (const float*)d_in[1];
  const float* W_A    = (const float*)d_in[2];
  const float* W_B    = (const float*)d_in[3];
  const float* W_C    = (const float*)d_in[4];
  const float* b_C    = (const float*)d_in[5];
  const float* W_ctrl = (const float*)d_in[6];
  const float* b_ctrl = (const float*)d_in[7];
  const float* W1     = (const float*)d_in[8];
  const float* b1     = (const float*)d_in[9];
  const float* W2     = (const float*)d_in[10];
  const float* b2     = (const float*)d_in[11];
  float* out = (float*)d_out;

  dim3 grid(B_SZ / ROWS);   // 256 blocks, 1/CU, 2 waves each
  dim3 block(THREADS);
  hipLaunchKernelGGL(ssm_2w_kernel, grid, block, 0, stream,
                     x, pl, W_A, W_B, W_C, b_C, W_ctrl, b_ctrl,
                     W1, b1, W2, b2, out);
}

// Round 11
// 285.680 us; speedup vs baseline: 2.1441x; 1.0000x over previous
//
#include <hip/hip_runtime.h>

#define B_SZ   4096
#define T_SZ   512
#define F_SZ   32
#define S_SZ   64
#define H_SZ   128
#define OUT_SZ 32
#define PH_SZ  6

#define ROWS    16    // batch rows per block -> 256 blocks
#define THREADS 128   // 2 waves; wave w owns states [32w, 32w+32) (2 MFMA tiles)

typedef __attribute__((ext_vector_type(8))) _Float16 f16x8;
typedef __attribute__((ext_vector_type(2))) __fp16 fp16v2;
typedef __attribute__((ext_vector_type(4))) float f32x4;

union F16Frag { _Float16 h[8]; f16x8 v; uint u[4]; };
union H2U { fp16v2 h; uint u; };

// one v_cvt_pkrtz_f16_f32: packs two f32 -> 2x f16 in a dword
__device__ __forceinline__ uint pk16(float a, float b) {
  H2U x; x.h = __builtin_amdgcn_cvt_pkrtz(a, b); return x.u;
}

#define MFMA(a, b, c) __builtin_amdgcn_mfma_f32_16x16x32_f16((a), (b), (c), 0, 0, 0)

// Exchange fence, HK-style (guide §5 / rule #18): NO "memory" clobber anywhere,
// so the backend does NOT insert s_waitcnt vmcnt(0) -- the global x prefetch
// stays in flight across the barrier. Ordering is pinned by sched_barrier(0).
#define EXCHANGE_FENCE() do {                      \
    __builtin_amdgcn_sched_barrier(0);             \
    asm volatile("s_waitcnt lgkmcnt(0)");          \
    __builtin_amdgcn_s_barrier();                  \
    __builtin_amdgcn_sched_barrier(0);             \
  } while (0)

__global__ __launch_bounds__(THREADS, 2) void ssm_2w_kernel(
    const float* __restrict__ x, const float* __restrict__ pl,
    const float* __restrict__ W_A, const float* __restrict__ W_B,
    const float* __restrict__ W_C, const float* __restrict__ b_C,
    const float* __restrict__ W_ctrl, const float* __restrict__ b_ctrl,
    const float* __restrict__ W1, const float* __restrict__ b1,
    const float* __restrict__ W2, const float* __restrict__ b2,
    float* __restrict__ out) {
  // state exchange: [buf][col*128 + swizzled(k*2)]; 64 fp16 states per col
  __shared__ __align__(16) char  s_state[2][2048];   // 4 KB
  __shared__ __align__(16) float s_final[ROWS][68];
  __shared__ __align__(16) float s_obs[ROWS][132];
  __shared__ __align__(16) float s_h1[ROWS][132];

  const int tid  = threadIdx.x;
  const int lane = tid & 63;
  const int wv2  = tid >> 6;     // 0..1: owns tiles {2wv2, 2wv2+1}
  const int l15  = lane & 15;    // batch col
  const int g    = lane >> 4;    // k-group / D row group
  const int rb   = blockIdx.x * ROWS;
  const int rg   = rb + l15;
  const float SC = 2.8853900817779268f;   // 2*log2(e): folds tanh exp arg

  // ---- weight frags: A single fp16 plane; W_B fp16 ----
  F16Frag Ah[2][2], Wb[2];
  f32x4 ctrl[2];
#pragma unroll
  for (int tt = 0; tt < 2; ++tt) {
    const int t = 2 * wv2 + tt;
#pragma unroll
    for (int kh = 0; kh < 2; ++kh) {
      const float* ap = W_A + (size_t)(16 * t + l15) * S_SZ + 32 * kh + 8 * g;
#pragma unroll
      for (int j = 0; j < 8; ++j) Ah[tt][kh].h[j] = (_Float16)(ap[j] * SC);
    }
    const float* wp = W_B + (size_t)(16 * t + l15) * F_SZ + 8 * g;
#pragma unroll
    for (int j = 0; j < 8; ++j) Wb[tt].h[j] = (_Float16)(wp[j] * SC);
    // control (SC-scaled), C/D layout: lane holds states 16t+4g+q, col rg
#pragma unroll
    for (int q = 0; q < 4; ++q) {
      const int i = 16 * t + 4 * g + q;
      float c = b_ctrl[i];
#pragma unroll
      for (int p = 0; p < PH_SZ; ++p)
        c = fmaf(W_ctrl[i * PH_SZ + p], pl[(size_t)rg * PH_SZ + p], c);
      ctrl[tt][q] = c * SC;
    }
  }

  // x: lane reads x[rg][t][8g .. 8g+7]
  const float* xg = x + (size_t)rg * T_SZ * F_SZ + 8 * g;

  // LDS offsets, XOR-swizzled. Write: 2x ds_write_b64 (one per tile).
  const int swz = (l15 & 7) << 4;
  const int wr0 = l15 * 128 + (((32 * wv2 + 4 * g) * 2) ^ swz);
  const int wr1 = l15 * 128 + (((32 * wv2 + 16 + 4 * g) * 2) ^ swz);
  const int rd0 = l15 * 128 + ((16 * g) ^ swz);          // k = 8g..8g+7
  const int rd1 = l15 * 128 + ((64 + 16 * g) ^ swz);     // k = 32+8g..

  f16x8 sh0, sh1;
#pragma unroll
  for (int j = 0; j < 8; ++j) { sh0[j] = (_Float16)0.f; sh1[j] = (_Float16)0.f; }

  // ---- prologue: base for t=0; prefetch x[1] (xB), x[2] (xA) ----
  f32x4 base0, base1;
  {
    float4 f0 = *(const float4*)(xg);
    float4 f1 = *(const float4*)(xg + 4);
    F16Frag xf;
    xf.u[0] = pk16(f0.x, f0.y); xf.u[1] = pk16(f0.z, f0.w);
    xf.u[2] = pk16(f1.x, f1.y); xf.u[3] = pk16(f1.z, f1.w);
    base0 = MFMA(Wb[0].v, xf.v, ctrl[0]);
    base1 = MFMA(Wb[1].v, xf.v, ctrl[1]);
  }
  float4 xB0 = *(const float4*)(xg + F_SZ);
  float4 xB1 = *(const float4*)(xg + F_SZ + 4);
  float4 xA0 = *(const float4*)(xg + 2 * F_SZ);
  float4 xA1 = *(const float4*)(xg + 2 * F_SZ + 4);

  // STEP(T_): state T_ -> T_+1. Two 2-deep MFMA chains (one per tile).
  // X regs hold x[T_+1] (consumed for next base); reloaded with x[T_+3].
#define STEP(T_, X0_, X1_, NB_, LAST_)                                          \
  {                                                                             \
    f32x4 P0 = MFMA(Ah[0][0].v, sh0, base0);                                    \
    f32x4 P1 = MFMA(Ah[1][0].v, sh0, base1);                                    \
    P0 = MFMA(Ah[0][1].v, sh1, P0);                                             \
    P1 = MFMA(Ah[1][1].v, sh1, P1);                                             \
    float v00, v01, v02, v03, v10, v11, v12, v13;                               \
    v00 = fmaf(-2.0f, __builtin_amdgcn_rcpf(__builtin_amdgcn_exp2f(P0[0]) + 1.0f), 1.0f); \
    v01 = fmaf(-2.0f, __builtin_amdgcn_rcpf(__builtin_amdgcn_exp2f(P0[1]) + 1.0f), 1.0f); \
    v02 = fmaf(-2.0f, __builtin_amdgcn_rcpf(__builtin_amdgcn_exp2f(P0[2]) + 1.0f), 1.0f); \
    v03 = fmaf(-2.0f, __builtin_amdgcn_rcpf(__builtin_amdgcn_exp2f(P0[3]) + 1.0f), 1.0f); \
    v10 = fmaf(-2.0f, __builtin_amdgcn_rcpf(__builtin_amdgcn_exp2f(P1[0]) + 1.0f), 1.0f); \
    v11 = fmaf(-2.0f, __builtin_amdgcn_rcpf(__builtin_amdgcn_exp2f(P1[1]) + 1.0f), 1.0f); \
    v12 = fmaf(-2.0f, __builtin_amdgcn_rcpf(__builtin_amdgcn_exp2f(P1[2]) + 1.0f), 1.0f); \
    v13 = fmaf(-2.0f, __builtin_amdgcn_rcpf(__builtin_amdgcn_exp2f(P1[3]) + 1.0f), 1.0f); \
    *(uint2*)(&s_state[NB_][wr0]) = make_uint2(pk16(v00, v01), pk16(v02, v03)); \
    *(uint2*)(&s_state[NB_][wr1]) = make_uint2(pk16(v10, v11), pk16(v12, v13)); \
    if (LAST_) {                                                                \
      *(float4*)(&s_final[l15][16 * (2 * wv2) + 4 * g]) =                       \
          make_float4(v00, v01, v02, v03);                                      \
      *(float4*)(&s_final[l15][16 * (2 * wv2 + 1) + 4 * g]) =                   \
          make_float4(v10, v11, v12, v13);                                      \
    }                                                                           \
    EXCHANGE_FENCE();                                                           \
    sh0 = *(const f16x8*)(&s_state[NB_][rd0]);                                  \
    sh1 = *(const f16x8*)(&s_state[NB_][rd1]);                                  \
    /* next base in the ds_read shadow */                                       \
    F16Frag xf;                                                                 \
    xf.u[0] = pk16(X0_.x, X0_.y); xf.u[1] = pk16(X0_.z, X0_.w);                 \
    xf.u[2] = pk16(X1_.x, X1_.y); xf.u[3] = pk16(X1_.z, X1_.w);                 \
    {                                                                           \
      const int tn_ = ((T_) + 3) & (T_SZ - 1);                                  \
      X0_ = *(const float4*)(xg + (size_t)tn_ * F_SZ);                          \
      X1_ = *(const float4*)(xg + (size_t)tn_ * F_SZ + 4);                      \
    }                                                                           \
    base0 = MFMA(Wb[0].v, xf.v, ctrl[0]);                                       \
    base1 = MFMA(Wb[1].v, xf.v, ctrl[1]);                                       \
  }

  for (int t = 0; t < T_SZ; t += 2) {
    STEP(t,     xB0, xB1, 1, false)
    STEP(t + 1, xA0, xA1, 0, (t == T_SZ - 2))
  }
#undef STEP

  // ---- tail projections (128 threads: 16 rows x 8 col-threads) ----
  __syncthreads();
  const int rt = tid >> 3;   // 0..15
  const int ct = tid & 7;    // 0..7

#pragma unroll
  for (int k = 0; k < 16; ++k) {
    const int h = ct + 8 * k;
    float acc = b_C[h];
    const float4* wc = (const float4*)(W_C + (size_t)h * S_SZ);
    const float4* sv = (const float4*)(&s_final[rt][0]);
#pragma unroll
    for (int j = 0; j < S_SZ / 4; ++j) {
      float4 w = wc[j]; float4 s = sv[j];
      acc = fmaf(w.x, s.x, acc); acc = fmaf(w.y, s.y, acc);
      acc = fmaf(w.z, s.z, acc); acc = fmaf(w.w, s.w, acc);
    }
    s_obs[rt][h] = acc;
  }
  __syncthreads();

#pragma unroll
  for (int k = 0; k < 16; ++k) {
    const int h = ct + 8 * k;
    float acc = b1[h];
    const float4* w1p = (const float4*)(W1 + (size_t)h * H_SZ);
    const float4* ov  = (const float4*)(&s_obs[rt][0]);
#pragma unroll
    for (int j = 0; j < H_SZ / 4; ++j) {
      float4 w = w1p[j]; float4 o = ov[j];
      acc = fmaf(w.x, o.x, acc); acc = fmaf(w.y, o.y, acc);
      acc = fmaf(w.z, o.z, acc); acc = fmaf(w.w, o.w, acc);
    }
    s_h1[rt][h] = fmaxf(acc, 0.0f);
  }
  __syncthreads();

#pragma unroll
  for (int it = 0; it < 4; ++it) {
    const int c = ct + 8 * it;
    float acc = b2[c];
    const float4* w2p = (const float4*)(W2 + (size_t)c * H_SZ);
    const float4* hv  = (const float4*)(&s_h1[rt][0]);
#pragma unroll
    for (int j = 0; j < H_SZ / 4; ++j) {
      float4 w = w2p[j]; float4 h = hv[j];
      acc = fmaf(w.x, h.x, acc); acc = fmaf(w.y, h.y, acc);
      acc = fmaf(w.z, h.z, acc); acc = fmaf(w.w, h.w, acc);
    }
    out[(size_t)(rb + rt) * OUT_SZ + c] = acc;
  }
}

extern "C" void kernel_launch(void* const* d_in, const int* in_sizes, int n_in,
                              void* d_out, int out_size, void* d_ws, size_t ws_size,
                              hipStream_t stream) {
  (void)in_sizes; (void)n_in; (void)out_size; (void)d_ws; (void)ws_size;
  const float* x      = (const float*)d_in[0];
  const float* pl     = (const float*)d_in[1];
  const float* W_A    = (const float*)d_in[2];
  const float* W_B    = (const float*)d_in[3];
  const float* W_C    = (const float*)d_in[4];
  const float* b_C    = (const float*)d_in[5];
  const float* W_ctrl = (const float*)d_in[6];
  const float* b_ctrl = (const float*)d_in[7];
  const float* W1     = (const float*)d_in[8];
  const float* b1     = (const float*)d_in[9];
  const float* W2     = (const float*)d_in[10];
  const float* b2     = (const float*)d_in[11];
  float* out = (float*)d_out;

  dim3 grid(B_SZ / ROWS);   // 256 blocks, 1/CU, 2 waves each
  dim3 block(THREADS);
  hipLaunchKernelGGL(ssm_2w_kernel, grid, block, 0, stream,
                     x, pl, W_A, W_B, W_C, b_C, W_ctrl, b_ctrl,
                     W1, b1, W2, b2, out);
}